// Round 1
// baseline (1166.084 us; speedup 1.0000x reference)
//
#include <hip/hip_runtime.h>
#include <cstdint>
#include <cstddef>

#define D 128
#define TILE_M 128

// ---------------------------------------------------------------------------
// SpMM scatter: out[dst[e]][d] += val[e] * h[src[e]][d]
// One thread per (edge, dim). A wave (64 lanes) covers half the dims of one
// edge -> val/src/dst loads are wave-uniform (broadcast), gather + atomic
// addresses are 256B-contiguous runs.
// ---------------------------------------------------------------------------
__global__ __launch_bounds__(256) void spmm_atomic(
    const float* __restrict__ h, const float* __restrict__ val,
    const int* __restrict__ src, const int* __restrict__ dst,
    float* __restrict__ out, int E) {
  long long gid = (long long)blockIdx.x * 256 + threadIdx.x;
  int e = (int)(gid >> 7);
  if (e >= E) return;
  int d = (int)(gid & 127);
  float v = val[e];
  int s = src[e];
  int t = dst[e];
  float m = v * h[(size_t)s * D + d];
  unsafeAtomicAdd(&out[(size_t)t * D + d], m);
}

// ---------------------------------------------------------------------------
// Dense layer: out[i][j] = act( sum_k in[i][k] * W[j][k] + b[j] )
// Block = 256 threads, output tile 128 rows x 128 cols, k-tiled by 32.
// LDS holds transposed chunks Hs[k][r], Ws[k][j] (row stride 132 floats so
// float4 reads stay 16B-aligned). Compute thread (rq=tid&31, jg=tid>>5)
// owns rows 4rq..4rq+3, cols 16jg..16jg+15:
//   per k: 1x ds_read_b128 (4 rows of H, consecutive lanes -> consecutive
//   addrs, conflict-free) + 4x ds_read_b128 (W, wave-uniform -> broadcast),
//   then 64 v_fma_f32.
// ---------------------------------------------------------------------------
__global__ __launch_bounds__(256) void dense_layer(
    const float* __restrict__ in, const float* __restrict__ W,
    const float* __restrict__ bias, float* __restrict__ out,
    int M, int apply_sigmoid) {
  __shared__ float Hs[32 * 132];
  __shared__ float Ws[32 * 132];

  const int tid = threadIdx.x;
  const int row0 = blockIdx.x * TILE_M;
  const int rq = tid & 31;   // row quad: rows 4rq..4rq+3
  const int jg = tid >> 5;   // col group: cols 16jg..16jg+15

  float acc[4][16];
#pragma unroll
  for (int i = 0; i < 4; ++i)
#pragma unroll
    for (int j = 0; j < 16; ++j) acc[i][j] = 0.0f;

  const float4* in4 = (const float4*)in;
  const float4* W4  = (const float4*)W;
  const float4* Hs4 = (const float4*)Hs;
  const float4* Ws4 = (const float4*)Ws;

  for (int k0 = 0; k0 < D; k0 += 32) {
    // Stage H chunk (128 rows x 32 k) and W chunk (128 j x 32 k), transposed.
    // 1024 float4 items each; item i -> (r = i>>3, c4 = i&7).
#pragma unroll
    for (int it = 0; it < 4; ++it) {
      int i = tid + it * 256;
      int r  = i >> 3;
      int c4 = i & 7;
      float4 g = make_float4(0.f, 0.f, 0.f, 0.f);
      if (row0 + r < M) g = in4[(size_t)(row0 + r) * (D / 4) + (k0 / 4) + c4];
      Hs[(4 * c4 + 0) * 132 + r] = g.x;
      Hs[(4 * c4 + 1) * 132 + r] = g.y;
      Hs[(4 * c4 + 2) * 132 + r] = g.z;
      Hs[(4 * c4 + 3) * 132 + r] = g.w;
      float4 w = W4[(size_t)r * (D / 4) + (k0 / 4) + c4];  // r plays the j role
      Ws[(4 * c4 + 0) * 132 + r] = w.x;
      Ws[(4 * c4 + 1) * 132 + r] = w.y;
      Ws[(4 * c4 + 2) * 132 + r] = w.z;
      Ws[(4 * c4 + 3) * 132 + r] = w.w;
    }
    __syncthreads();

#pragma unroll 8
    for (int k = 0; k < 32; ++k) {
      float4 h4 = Hs4[k * 33 + rq];
      float4 w0 = Ws4[k * 33 + jg * 4 + 0];
      float4 w1 = Ws4[k * 33 + jg * 4 + 1];
      float4 w2 = Ws4[k * 33 + jg * 4 + 2];
      float4 w3 = Ws4[k * 33 + jg * 4 + 3];
      float hv[4] = {h4.x, h4.y, h4.z, h4.w};
      float wv[16] = {w0.x, w0.y, w0.z, w0.w, w1.x, w1.y, w1.z, w1.w,
                      w2.x, w2.y, w2.z, w2.w, w3.x, w3.y, w3.z, w3.w};
#pragma unroll
      for (int ri = 0; ri < 4; ++ri)
#pragma unroll
        for (int jj = 0; jj < 16; ++jj) acc[ri][jj] += hv[ri] * wv[jj];
    }
    __syncthreads();
  }

  // Epilogue: bias (+ sigmoid), store 4 float4 per row.
  const float4* bias4 = (const float4*)bias;
  float4 bv[4];
#pragma unroll
  for (int c = 0; c < 4; ++c) bv[c] = bias4[jg * 4 + c];

  float4* out4 = (float4*)out;
#pragma unroll
  for (int ri = 0; ri < 4; ++ri) {
    int row = row0 + 4 * rq + ri;
    if (row < M) {
#pragma unroll
      for (int c = 0; c < 4; ++c) {
        float4 v;
        v.x = acc[ri][4 * c + 0] + bv[c].x;
        v.y = acc[ri][4 * c + 1] + bv[c].y;
        v.z = acc[ri][4 * c + 2] + bv[c].z;
        v.w = acc[ri][4 * c + 3] + bv[c].w;
        if (apply_sigmoid) {
          v.x = 1.0f / (1.0f + __expf(-v.x));
          v.y = 1.0f / (1.0f + __expf(-v.y));
          v.z = 1.0f / (1.0f + __expf(-v.z));
          v.w = 1.0f / (1.0f + __expf(-v.w));
        }
        out4[(size_t)row * (D / 4) + jg * 4 + c] = v;
      }
    }
  }
}

// ---------------------------------------------------------------------------
// Row softmax over 128 features. One wave per row, 2 elements per lane.
// ---------------------------------------------------------------------------
__global__ __launch_bounds__(256) void softmax_rows(
    const float* __restrict__ in, float* __restrict__ out, int M) {
  int wave = threadIdx.x >> 6;
  int lane = threadIdx.x & 63;
  int row = blockIdx.x * 4 + wave;
  if (row >= M) return;
  float a = in[(size_t)row * D + lane];
  float b = in[(size_t)row * D + 64 + lane];
  float m = fmaxf(a, b);
#pragma unroll
  for (int off = 32; off; off >>= 1) m = fmaxf(m, __shfl_xor(m, off));
  float ea = __expf(a - m);
  float eb = __expf(b - m);
  float s = ea + eb;
#pragma unroll
  for (int off = 32; off; off >>= 1) s += __shfl_xor(s, off);
  float inv = 1.0f / s;
  out[(size_t)row * D + lane] = ea * inv;
  out[(size_t)row * D + 64 + lane] = eb * inv;
}

// ---------------------------------------------------------------------------
extern "C" void kernel_launch(void* const* d_in, const int* in_sizes, int n_in,
                              void* d_out, int out_size, void* d_ws, size_t ws_size,
                              hipStream_t stream) {
  const float* x  = (const float*)d_in[0];
  const float* ev = (const float*)d_in[1];
  const float* W1 = (const float*)d_in[2];
  const float* b1 = (const float*)d_in[3];
  const float* W2 = (const float*)d_in[4];
  const float* b2 = (const float*)d_in[5];
  const float* W3 = (const float*)d_in[6];
  const float* b3 = (const float*)d_in[7];
  const int* es = (const int*)d_in[8];
  const int* ed = (const int*)d_in[9];

  const int N = in_sizes[0] / D;
  const int E = in_sizes[1];

  float* A = (float*)d_ws;                 // spmm accumulator
  float* B = A + (size_t)N * D;            // dense output / next spmm input
  float* outf = (float*)d_out;

  const size_t nd_bytes = (size_t)N * D * sizeof(float);
  const int spmm_grid  = (int)(((long long)E * D + 255) / 256);
  const int dense_grid = (N + TILE_M - 1) / TILE_M;
  const int soft_grid  = (N + 3) / 4;

  // Layer 1
  hipMemsetAsync(A, 0, nd_bytes, stream);
  spmm_atomic<<<spmm_grid, 256, 0, stream>>>(x, ev, es, ed, A, E);
  dense_layer<<<dense_grid, 256, 0, stream>>>(A, W1, b1, B, N, 1);
  // Layer 2
  hipMemsetAsync(A, 0, nd_bytes, stream);
  spmm_atomic<<<spmm_grid, 256, 0, stream>>>(B, ev, es, ed, A, E);
  dense_layer<<<dense_grid, 256, 0, stream>>>(A, W2, b2, B, N, 1);
  // Layer 3 (no sigmoid) + softmax
  hipMemsetAsync(A, 0, nd_bytes, stream);
  spmm_atomic<<<spmm_grid, 256, 0, stream>>>(B, ev, es, ed, A, E);
  dense_layer<<<dense_grid, 256, 0, stream>>>(A, W3, b3, B, N, 0);
  softmax_rows<<<soft_grid, 256, 0, stream>>>(B, outf, N);
}

// Round 2
// 567.402 us; speedup vs baseline: 2.0551x; 2.0551x over previous
//
#include <hip/hip_runtime.h>
#include <cstdint>
#include <cstddef>

#define D 128
#define TILE_M 128
#define NNODE_MAX 1
#define SCAN_CHUNK 1024  // elements per scan block (256 threads x 4)

// ---------------------------------------------------------------------------
// Counting-sort pipeline: build dst-sorted CSR of (src, val) once per call.
// ---------------------------------------------------------------------------
__global__ __launch_bounds__(256) void hist_kernel(
    const int* __restrict__ dst, int* __restrict__ count, int E) {
  int e = blockIdx.x * 256 + threadIdx.x;
  if (e < E) atomicAdd(&count[dst[e]], 1);
}

// Per-block exclusive scan of `count` (1024 elems/block) into rowptr;
// block totals into blockSums.
__global__ __launch_bounds__(256) void scan_blocks(
    const int* __restrict__ count, int* __restrict__ rowptr,
    int* __restrict__ blockSums, int n) {
  __shared__ int sdata[256];
  const int tid = threadIdx.x;
  const int base = blockIdx.x * SCAN_CHUNK;
  int v[4];
#pragma unroll
  for (int k = 0; k < 4; ++k) {
    int idx = base + tid * 4 + k;
    v[k] = (idx < n) ? count[idx] : 0;
  }
  int s = v[0] + v[1] + v[2] + v[3];
  sdata[tid] = s;
  __syncthreads();
  for (int off = 1; off < 256; off <<= 1) {
    int x = (tid >= off) ? sdata[tid - off] : 0;
    __syncthreads();
    sdata[tid] += x;
    __syncthreads();
  }
  int run = sdata[tid] - s;  // exclusive prefix of this thread's chunk
#pragma unroll
  for (int k = 0; k < 4; ++k) {
    int idx = base + tid * 4 + k;
    if (idx < n) rowptr[idx] = run;
    run += v[k];
  }
  if (tid == 255) blockSums[blockIdx.x] = sdata[255];
}

// Serial exclusive scan of the (tiny) block-sums array.
__global__ void scan_top(int* __restrict__ bs, int nblk) {
  int run = 0;
  for (int i = 0; i < nblk; ++i) { int t = bs[i]; bs[i] = run; run += t; }
}

__global__ __launch_bounds__(256) void add_offsets(
    int* __restrict__ rowptr, int* __restrict__ cursor,
    const int* __restrict__ bs, int n) {
  int i = blockIdx.x * 256 + threadIdx.x;
  if (i < n) {
    int v = rowptr[i] + bs[i >> 10];
    rowptr[i] = v;
    cursor[i] = v;
  }
}

__global__ __launch_bounds__(256) void scatter_edges(
    const int* __restrict__ src, const int* __restrict__ dst,
    const float* __restrict__ val, int* __restrict__ cursor,
    int2* __restrict__ sorted, int E) {
  int e = blockIdx.x * 256 + threadIdx.x;
  if (e < E) {
    int t = dst[e];
    int pos = atomicAdd(&cursor[t], 1);
    sorted[pos] = make_int2(src[e], __float_as_int(val[e]));
  }
}

// ---------------------------------------------------------------------------
// CSR gather SpMM: out[i] = sum_j val_j * h[src_j]. One wave per row;
// each lane owns dims (lane, lane+64). Edge records broadcast; h-row
// gathers are coalesced 256B runs; single coalesced write per row.
// ---------------------------------------------------------------------------
__global__ __launch_bounds__(256) void spmm_csr(
    const float* __restrict__ h, const int2* __restrict__ sorted,
    const int* __restrict__ rowptr, const int* __restrict__ count,
    float* __restrict__ out, int n) {
  int wave = threadIdx.x >> 6;
  int lane = threadIdx.x & 63;
  int row = blockIdx.x * 4 + wave;
  if (row >= n) return;
  int start = rowptr[row];
  int len = count[row];
  float a0 = 0.f, a1 = 0.f;
  int j = 0;
  for (; j + 2 <= len; j += 2) {
    int2 e0 = sorted[start + j];
    int2 e1 = sorted[start + j + 1];
    const float* h0 = h + (size_t)e0.x * D;
    const float* h1 = h + (size_t)e1.x * D;
    float v0 = __int_as_float(e0.y);
    float v1 = __int_as_float(e1.y);
    float x00 = h0[lane], x01 = h0[64 + lane];
    float x10 = h1[lane], x11 = h1[64 + lane];
    a0 += v0 * x00; a1 += v0 * x01;
    a0 += v1 * x10; a1 += v1 * x11;
  }
  if (j < len) {
    int2 e0 = sorted[start + j];
    const float* h0 = h + (size_t)e0.x * D;
    float v0 = __int_as_float(e0.y);
    a0 += v0 * h0[lane];
    a1 += v0 * h0[64 + lane];
  }
  out[(size_t)row * D + lane] = a0;
  out[(size_t)row * D + 64 + lane] = a1;
}

// ---------------------------------------------------------------------------
// Dense layer: out[i][j] = act( sum_k in[i][k] * W[j][k] + b[j] )
// (unchanged from round 1 — ~35us, not the bottleneck)
// ---------------------------------------------------------------------------
__global__ __launch_bounds__(256) void dense_layer(
    const float* __restrict__ in, const float* __restrict__ W,
    const float* __restrict__ bias, float* __restrict__ out,
    int M, int apply_sigmoid) {
  __shared__ float Hs[32 * 132];
  __shared__ float Ws[32 * 132];

  const int tid = threadIdx.x;
  const int row0 = blockIdx.x * TILE_M;
  const int rq = tid & 31;
  const int jg = tid >> 5;

  float acc[4][16];
#pragma unroll
  for (int i = 0; i < 4; ++i)
#pragma unroll
    for (int j = 0; j < 16; ++j) acc[i][j] = 0.0f;

  const float4* in4 = (const float4*)in;
  const float4* W4  = (const float4*)W;
  const float4* Hs4 = (const float4*)Hs;
  const float4* Ws4 = (const float4*)Ws;

  for (int k0 = 0; k0 < D; k0 += 32) {
#pragma unroll
    for (int it = 0; it < 4; ++it) {
      int i = tid + it * 256;
      int r  = i >> 3;
      int c4 = i & 7;
      float4 g = make_float4(0.f, 0.f, 0.f, 0.f);
      if (row0 + r < M) g = in4[(size_t)(row0 + r) * (D / 4) + (k0 / 4) + c4];
      Hs[(4 * c4 + 0) * 132 + r] = g.x;
      Hs[(4 * c4 + 1) * 132 + r] = g.y;
      Hs[(4 * c4 + 2) * 132 + r] = g.z;
      Hs[(4 * c4 + 3) * 132 + r] = g.w;
      float4 w = W4[(size_t)r * (D / 4) + (k0 / 4) + c4];
      Ws[(4 * c4 + 0) * 132 + r] = w.x;
      Ws[(4 * c4 + 1) * 132 + r] = w.y;
      Ws[(4 * c4 + 2) * 132 + r] = w.z;
      Ws[(4 * c4 + 3) * 132 + r] = w.w;
    }
    __syncthreads();

#pragma unroll 8
    for (int k = 0; k < 32; ++k) {
      float4 h4 = Hs4[k * 33 + rq];
      float4 w0 = Ws4[k * 33 + jg * 4 + 0];
      float4 w1 = Ws4[k * 33 + jg * 4 + 1];
      float4 w2 = Ws4[k * 33 + jg * 4 + 2];
      float4 w3 = Ws4[k * 33 + jg * 4 + 3];
      float hv[4] = {h4.x, h4.y, h4.z, h4.w};
      float wv[16] = {w0.x, w0.y, w0.z, w0.w, w1.x, w1.y, w1.z, w1.w,
                      w2.x, w2.y, w2.z, w2.w, w3.x, w3.y, w3.z, w3.w};
#pragma unroll
      for (int ri = 0; ri < 4; ++ri)
#pragma unroll
        for (int jj = 0; jj < 16; ++jj) acc[ri][jj] += hv[ri] * wv[jj];
    }
    __syncthreads();
  }

  const float4* bias4 = (const float4*)bias;
  float4 bv[4];
#pragma unroll
  for (int c = 0; c < 4; ++c) bv[c] = bias4[jg * 4 + c];

  float4* out4 = (float4*)out;
#pragma unroll
  for (int ri = 0; ri < 4; ++ri) {
    int row = row0 + 4 * rq + ri;
    if (row < M) {
#pragma unroll
      for (int c = 0; c < 4; ++c) {
        float4 v;
        v.x = acc[ri][4 * c + 0] + bv[c].x;
        v.y = acc[ri][4 * c + 1] + bv[c].y;
        v.z = acc[ri][4 * c + 2] + bv[c].z;
        v.w = acc[ri][4 * c + 3] + bv[c].w;
        if (apply_sigmoid) {
          v.x = 1.0f / (1.0f + __expf(-v.x));
          v.y = 1.0f / (1.0f + __expf(-v.y));
          v.z = 1.0f / (1.0f + __expf(-v.z));
          v.w = 1.0f / (1.0f + __expf(-v.w));
        }
        out4[(size_t)row * (D / 4) + jg * 4 + c] = v;
      }
    }
  }
}

// ---------------------------------------------------------------------------
// Row softmax over 128 features. One wave per row, 2 elems/lane.
// ---------------------------------------------------------------------------
__global__ __launch_bounds__(256) void softmax_rows(
    const float* __restrict__ in, float* __restrict__ out, int M) {
  int wave = threadIdx.x >> 6;
  int lane = threadIdx.x & 63;
  int row = blockIdx.x * 4 + wave;
  if (row >= M) return;
  float a = in[(size_t)row * D + lane];
  float b = in[(size_t)row * D + 64 + lane];
  float m = fmaxf(a, b);
#pragma unroll
  for (int off = 32; off; off >>= 1) m = fmaxf(m, __shfl_xor(m, off));
  float ea = __expf(a - m);
  float eb = __expf(b - m);
  float s = ea + eb;
#pragma unroll
  for (int off = 32; off; off >>= 1) s += __shfl_xor(s, off);
  float inv = 1.0f / s;
  out[(size_t)row * D + lane] = ea * inv;
  out[(size_t)row * D + 64 + lane] = eb * inv;
}

// ---------------------------------------------------------------------------
extern "C" void kernel_launch(void* const* d_in, const int* in_sizes, int n_in,
                              void* d_out, int out_size, void* d_ws, size_t ws_size,
                              hipStream_t stream) {
  const float* x  = (const float*)d_in[0];
  const float* ev = (const float*)d_in[1];
  const float* W1 = (const float*)d_in[2];
  const float* b1 = (const float*)d_in[3];
  const float* W2 = (const float*)d_in[4];
  const float* b2 = (const float*)d_in[5];
  const float* W3 = (const float*)d_in[6];
  const float* b3 = (const float*)d_in[7];
  const int* es = (const int*)d_in[8];
  const int* ed = (const int*)d_in[9];

  const int N = in_sizes[0] / D;
  const int E = in_sizes[1];

  // Workspace layout
  char* p = (char*)d_ws;
  float* A = (float*)p;            p += (size_t)N * D * sizeof(float);
  float* B = (float*)p;            p += (size_t)N * D * sizeof(float);
  int2* sorted = (int2*)p;         p += (size_t)E * sizeof(int2);
  int* count  = (int*)p;           p += (size_t)N * sizeof(int);
  int* rowptr = (int*)p;           p += (size_t)N * sizeof(int);
  int* cursor = (int*)p;           p += (size_t)N * sizeof(int);
  int* blockSums = (int*)p;        p += 1024 * sizeof(int);
  float* outf = (float*)d_out;

  const int eblk = (E + 255) / 256;
  const int nblk256 = (N + 255) / 256;
  const int nblkScan = (N + SCAN_CHUNK - 1) / SCAN_CHUNK;
  const int rowgrid = (N + 3) / 4;
  const int dense_grid = (N + TILE_M - 1) / TILE_M;

  // --- Build dst-sorted CSR (once; reused by all 3 layers) ---
  hipMemsetAsync(count, 0, (size_t)N * sizeof(int), stream);
  hist_kernel<<<eblk, 256, 0, stream>>>(ed, count, E);
  scan_blocks<<<nblkScan, 256, 0, stream>>>(count, rowptr, blockSums, N);
  scan_top<<<1, 1, 0, stream>>>(blockSums, nblkScan);
  add_offsets<<<nblk256, 256, 0, stream>>>(rowptr, cursor, blockSums, N);
  scatter_edges<<<eblk, 256, 0, stream>>>(es, ed, ev, cursor, sorted, E);

  // --- Layer 1 ---
  spmm_csr<<<rowgrid, 256, 0, stream>>>(x, sorted, rowptr, count, A, N);
  dense_layer<<<dense_grid, 256, 0, stream>>>(A, W1, b1, B, N, 1);
  // --- Layer 2 ---
  spmm_csr<<<rowgrid, 256, 0, stream>>>(B, sorted, rowptr, count, A, N);
  dense_layer<<<dense_grid, 256, 0, stream>>>(A, W2, b2, B, N, 1);
  // --- Layer 3 + softmax ---
  spmm_csr<<<rowgrid, 256, 0, stream>>>(B, sorted, rowptr, count, A, N);
  dense_layer<<<dense_grid, 256, 0, stream>>>(A, W3, b3, B, N, 0);
  softmax_rows<<<rowgrid, 256, 0, stream>>>(B, outf, N);
}

// Round 4
// 402.570 us; speedup vs baseline: 2.8966x; 1.4094x over previous
//
#include <hip/hip_runtime.h>
#include <hip/hip_bf16.h>
#include <cstdint>
#include <cstddef>

#define D 128
#define SCAN_CHUNK 1024

typedef __attribute__((ext_vector_type(8))) __bf16 bf16v8;
typedef __attribute__((ext_vector_type(4))) float f32v4;

// Round-to-nearest-even fp32 -> bf16 (bits), packed pair.
__device__ inline unsigned int pack_bf16x2(float a, float b) {
  unsigned int ua = __float_as_uint(a);
  unsigned int ub = __float_as_uint(b);
  ua = (ua + 0x7fffu + ((ua >> 16) & 1u)) >> 16;
  ub = (ub + 0x7fffu + ((ub >> 16) & 1u)) >> 16;
  return ua | (ub << 16);
}

// ---------------------------------------------------------------------------
// Counting-sort pipeline: build dst-sorted CSR of (src, val) once per call.
// ---------------------------------------------------------------------------
__global__ __launch_bounds__(256) void hist_kernel(
    const int* __restrict__ dst, int* __restrict__ count, int E) {
  int e = blockIdx.x * 256 + threadIdx.x;
  if (e < E) atomicAdd(&count[dst[e]], 1);
}

__global__ __launch_bounds__(256) void scan_blocks(
    const int* __restrict__ count, int* __restrict__ rowptr,
    int* __restrict__ blockSums, int n) {
  __shared__ int sdata[256];
  const int tid = threadIdx.x;
  const int base = blockIdx.x * SCAN_CHUNK;
  int v[4];
#pragma unroll
  for (int k = 0; k < 4; ++k) {
    int idx = base + tid * 4 + k;
    v[k] = (idx < n) ? count[idx] : 0;
  }
  int s = v[0] + v[1] + v[2] + v[3];
  sdata[tid] = s;
  __syncthreads();
  for (int off = 1; off < 256; off <<= 1) {
    int x = (tid >= off) ? sdata[tid - off] : 0;
    __syncthreads();
    sdata[tid] += x;
    __syncthreads();
  }
  int run = sdata[tid] - s;
#pragma unroll
  for (int k = 0; k < 4; ++k) {
    int idx = base + tid * 4 + k;
    if (idx < n) rowptr[idx] = run;
    run += v[k];
  }
  if (tid == 255) blockSums[blockIdx.x] = sdata[255];
}

// Parallel single-block exclusive scan of block sums (nblk <= 1024).
__global__ __launch_bounds__(256) void scan_top(int* __restrict__ bs, int nblk) {
  __shared__ int sdata[256];
  const int tid = threadIdx.x;
  int v[4];
#pragma unroll
  for (int k = 0; k < 4; ++k) {
    int idx = tid * 4 + k;
    v[k] = (idx < nblk) ? bs[idx] : 0;
  }
  int s = v[0] + v[1] + v[2] + v[3];
  sdata[tid] = s;
  __syncthreads();
  for (int off = 1; off < 256; off <<= 1) {
    int x = (tid >= off) ? sdata[tid - off] : 0;
    __syncthreads();
    sdata[tid] += x;
    __syncthreads();
  }
  int run = sdata[tid] - s;
#pragma unroll
  for (int k = 0; k < 4; ++k) {
    int idx = tid * 4 + k;
    if (idx < nblk) { int t = v[k]; bs[idx] = run; run += t; }
  }
}

__global__ __launch_bounds__(256) void add_offsets(
    int* __restrict__ rowptr, int* __restrict__ cursor,
    const int* __restrict__ bs, int n) {
  int i = blockIdx.x * 256 + threadIdx.x;
  if (i < n) {
    int v = rowptr[i] + bs[i >> 10];
    rowptr[i] = v;
    cursor[i] = v;
  }
}

__global__ __launch_bounds__(256) void scatter_edges(
    const int* __restrict__ src, const int* __restrict__ dst,
    const float* __restrict__ val, int* __restrict__ cursor,
    int2* __restrict__ sorted, int E) {
  int e = blockIdx.x * 256 + threadIdx.x;
  if (e < E) {
    int t = dst[e];
    int pos = atomicAdd(&cursor[t], 1);
    sorted[pos] = make_int2(src[e], __float_as_int(val[e]));
  }
}

// ---------------------------------------------------------------------------
// CSR gather SpMM, fp32 input rows -> bf16 output rows (layer 1: reads x).
// One wave per row; lane owns dims (2*lane, 2*lane+1). fp32 accumulate.
// ---------------------------------------------------------------------------
__global__ __launch_bounds__(256) void spmm_f32_bf16(
    const float* __restrict__ h, const int2* __restrict__ sorted,
    const int* __restrict__ rowptr, const int* __restrict__ count,
    unsigned int* __restrict__ out, int n) {
  int wave = threadIdx.x >> 6;
  int lane = threadIdx.x & 63;
  int row = blockIdx.x * 4 + wave;
  if (row >= n) return;
  int start = rowptr[row];
  int len = count[row];
  const float2* h2 = (const float2*)h;
  float a0 = 0.f, a1 = 0.f;
  int j = 0;
  for (; j + 2 <= len; j += 2) {
    int2 e0 = sorted[start + j];
    int2 e1 = sorted[start + j + 1];
    float2 x0 = h2[(size_t)e0.x * 64 + lane];
    float2 x1 = h2[(size_t)e1.x * 64 + lane];
    float v0 = __int_as_float(e0.y);
    float v1 = __int_as_float(e1.y);
    a0 += v0 * x0.x; a1 += v0 * x0.y;
    a0 += v1 * x1.x; a1 += v1 * x1.y;
  }
  if (j < len) {
    int2 e0 = sorted[start + j];
    float2 x0 = h2[(size_t)e0.x * 64 + lane];
    float v0 = __int_as_float(e0.y);
    a0 += v0 * x0.x; a1 += v0 * x0.y;
  }
  out[(size_t)row * 64 + lane] = pack_bf16x2(a0, a1);
}

// Same but bf16 input rows (layers 2,3).
__global__ __launch_bounds__(256) void spmm_bf16_bf16(
    const unsigned int* __restrict__ h, const int2* __restrict__ sorted,
    const int* __restrict__ rowptr, const int* __restrict__ count,
    unsigned int* __restrict__ out, int n) {
  int wave = threadIdx.x >> 6;
  int lane = threadIdx.x & 63;
  int row = blockIdx.x * 4 + wave;
  if (row >= n) return;
  int start = rowptr[row];
  int len = count[row];
  float a0 = 0.f, a1 = 0.f;
  int j = 0;
  for (; j + 2 <= len; j += 2) {
    int2 e0 = sorted[start + j];
    int2 e1 = sorted[start + j + 1];
    unsigned int u0 = h[(size_t)e0.x * 64 + lane];
    unsigned int u1 = h[(size_t)e1.x * 64 + lane];
    float v0 = __int_as_float(e0.y);
    float v1 = __int_as_float(e1.y);
    a0 += v0 * __uint_as_float(u0 << 16);
    a1 += v0 * __uint_as_float(u0 & 0xffff0000u);
    a0 += v1 * __uint_as_float(u1 << 16);
    a1 += v1 * __uint_as_float(u1 & 0xffff0000u);
  }
  if (j < len) {
    int2 e0 = sorted[start + j];
    unsigned int u0 = h[(size_t)e0.x * 64 + lane];
    float v0 = __int_as_float(e0.y);
    a0 += v0 * __uint_as_float(u0 << 16);
    a1 += v0 * __uint_as_float(u0 & 0xffff0000u);
  }
  out[(size_t)row * 64 + lane] = pack_bf16x2(a0, a1);
}

// ---------------------------------------------------------------------------
// Weight cast: W (3 matrices, fp32 128x128) -> bf16, once per call.
// ---------------------------------------------------------------------------
__global__ __launch_bounds__(256) void cast_w(
    const float* __restrict__ W1, const float* __restrict__ W2,
    const float* __restrict__ W3, unsigned short* __restrict__ out) {
  const float* src[3] = {W1, W2, W3};
  int m = blockIdx.y;
  int i = blockIdx.x * 256 + threadIdx.x;
  if (i < D * D) {
    unsigned int u = __float_as_uint(src[m][i]);
    out[(size_t)m * D * D + i] =
        (unsigned short)((u + 0x7fffu + ((u >> 16) & 1u)) >> 16);
  }
}

// ---------------------------------------------------------------------------
// Dense layer via bf16 MFMA 16x16x32: out[i][j] = act(sum_k in[i][k]*W[j][k]+b[j])
// Block = 256 thr / 4 waves, tile 128 rows x 128 cols, whole K=128 staged in
// LDS (bf16, row stride 136 -> conflict-balanced 16B reads).
// Wave w: rows 32w..32w+31 (2 m-tiles), all 8 n-tiles. fp32 accum in MFMA.
// A frag: A[m=lane&15][k=quad*8+j]; B frag: B[k=quad*8+j][n=lane&15] = W[n][k].
// C/D: col=lane&15, row=quad*4+reg  [measured m89/m91/m120].
// ---------------------------------------------------------------------------
__global__ __launch_bounds__(256) void dense_mfma(
    const unsigned short* __restrict__ in, const unsigned short* __restrict__ Wb,
    const float* __restrict__ bias, unsigned short* __restrict__ out,
    int M, int apply_sigmoid) {
  __shared__ __align__(16) unsigned short Hs[128 * 136];
  __shared__ __align__(16) unsigned short Ws[128 * 136];

  const int tid = threadIdx.x;
  const int w = tid >> 6;
  const int lane = tid & 63;
  const int lane15 = lane & 15;
  const int quad = lane >> 4;
  const int row0 = blockIdx.x * 128;

  // Stage H tile (128x128 bf16) and W (128x128 bf16) into LDS, 16B chunks.
  const uint4* in16 = (const uint4*)in;   // 16 chunks per row
  const uint4* w16  = (const uint4*)Wb;
#pragma unroll
  for (int it = 0; it < 8; ++it) {
    int c = it * 256 + tid;          // 0..2047
    int r = c >> 4;
    int ck = c & 15;
    uint4 g = make_uint4(0, 0, 0, 0);
    if (row0 + r < M) g = in16[(size_t)(row0 + r) * 16 + ck];
    *(uint4*)&Hs[r * 136 + ck * 8] = g;
    *(uint4*)&Ws[r * 136 + ck * 8] = w16[(size_t)r * 16 + ck];
  }
  __syncthreads();

  f32v4 acc[2][8];
#pragma unroll
  for (int mt = 0; mt < 2; ++mt)
#pragma unroll
    for (int nt = 0; nt < 8; ++nt) acc[mt][nt] = (f32v4){0.f, 0.f, 0.f, 0.f};

#pragma unroll
  for (int kt = 0; kt < 4; ++kt) {
    const int ko = kt * 32 + quad * 8;
    bf16v8 a0 = *(const bf16v8*)&Hs[(w * 32 + lane15) * 136 + ko];
    bf16v8 a1 = *(const bf16v8*)&Hs[(w * 32 + 16 + lane15) * 136 + ko];
#pragma unroll
    for (int nt = 0; nt < 8; ++nt) {
      bf16v8 b = *(const bf16v8*)&Ws[(nt * 16 + lane15) * 136 + ko];
      acc[0][nt] = __builtin_amdgcn_mfma_f32_16x16x32_bf16(a0, b, acc[0][nt], 0, 0, 0);
      acc[1][nt] = __builtin_amdgcn_mfma_f32_16x16x32_bf16(a1, b, acc[1][nt], 0, 0, 0);
    }
  }

  // Epilogue: bias (+sigmoid) in fp32, store bf16.
  float bv[8];
#pragma unroll
  for (int nt = 0; nt < 8; ++nt) bv[nt] = bias[nt * 16 + lane15];

#pragma unroll
  for (int mt = 0; mt < 2; ++mt) {
#pragma unroll
    for (int r = 0; r < 4; ++r) {
      int grow = row0 + w * 32 + mt * 16 + quad * 4 + r;
      if (grow < M) {
#pragma unroll
        for (int nt = 0; nt < 8; ++nt) {
          float v = acc[mt][nt][r] + bv[nt];
          if (apply_sigmoid) v = 1.0f / (1.0f + __expf(-v));
          unsigned int u = __float_as_uint(v);
          out[(size_t)grow * D + nt * 16 + lane15] =
              (unsigned short)((u + 0x7fffu + ((u >> 16) & 1u)) >> 16);
        }
      }
    }
  }
}

// ---------------------------------------------------------------------------
// Row softmax over 128 features, bf16 logits in, fp32 out.
// One wave per row; lane owns cols (2*lane, 2*lane+1).
// ---------------------------------------------------------------------------
__global__ __launch_bounds__(256) void softmax_rows(
    const unsigned int* __restrict__ in, float* __restrict__ out, int M) {
  int wave = threadIdx.x >> 6;
  int lane = threadIdx.x & 63;
  int row = blockIdx.x * 4 + wave;
  if (row >= M) return;
  unsigned int u = in[(size_t)row * 64 + lane];
  float a = __uint_as_float(u << 16);
  float b = __uint_as_float(u & 0xffff0000u);
  float m = fmaxf(a, b);
#pragma unroll
  for (int off = 32; off; off >>= 1) m = fmaxf(m, __shfl_xor(m, off));
  float ea = __expf(a - m);
  float eb = __expf(b - m);
  float s = ea + eb;
#pragma unroll
  for (int off = 32; off; off >>= 1) s += __shfl_xor(s, off);
  float inv = 1.0f / s;
  ((float2*)out)[(size_t)row * 64 + lane] = make_float2(ea * inv, eb * inv);
}

// ---------------------------------------------------------------------------
extern "C" void kernel_launch(void* const* d_in, const int* in_sizes, int n_in,
                              void* d_out, int out_size, void* d_ws, size_t ws_size,
                              hipStream_t stream) {
  const float* x  = (const float*)d_in[0];
  const float* ev = (const float*)d_in[1];
  const float* W1 = (const float*)d_in[2];
  const float* b1 = (const float*)d_in[3];
  const float* W2 = (const float*)d_in[4];
  const float* b2 = (const float*)d_in[5];
  const float* W3 = (const float*)d_in[6];
  const float* b3 = (const float*)d_in[7];
  const int* es = (const int*)d_in[8];
  const int* ed = (const int*)d_in[9];

  const int N = in_sizes[0] / D;
  const int E = in_sizes[1];

  // Workspace layout (all 16B-aligned)
  char* p = (char*)d_ws;
  unsigned int* BA = (unsigned int*)p; p += (size_t)N * 64 * sizeof(unsigned int);
  unsigned int* BB = (unsigned int*)p; p += (size_t)N * 64 * sizeof(unsigned int);
  int2* sorted = (int2*)p;          p += (size_t)E * sizeof(int2);
  unsigned short* Wb = (unsigned short*)p; p += 3 * (size_t)D * D * sizeof(unsigned short);
  int* count  = (int*)p;            p += (size_t)N * sizeof(int);
  int* rowptr = (int*)p;            p += (size_t)N * sizeof(int);
  int* cursor = (int*)p;            p += (size_t)N * sizeof(int);
  int* blockSums = (int*)p;         p += 1024 * sizeof(int);
  float* outf = (float*)d_out;

  const int eblk = (E + 255) / 256;
  const int nblk256 = (N + 255) / 256;
  const int nblkScan = (N + SCAN_CHUNK - 1) / SCAN_CHUNK;
  const int rowgrid = (N + 3) / 4;
  const int dense_grid = (N + 127) / 128;

  // --- Build dst-sorted CSR + bf16 weights (reused by all layers) ---
  (void)hipMemsetAsync(count, 0, (size_t)N * sizeof(int), stream);
  hist_kernel<<<eblk, 256, 0, stream>>>(ed, count, E);
  cast_w<<<dim3((D * D + 255) / 256, 3), 256, 0, stream>>>(W1, W2, W3, Wb);
  scan_blocks<<<nblkScan, 256, 0, stream>>>(count, rowptr, blockSums, N);
  scan_top<<<1, 256, 0, stream>>>(blockSums, nblkScan);
  add_offsets<<<nblk256, 256, 0, stream>>>(rowptr, cursor, blockSums, N);
  scatter_edges<<<eblk, 256, 0, stream>>>(es, ed, ev, cursor, sorted, E);

  // --- Layer 1: spmm(x fp32) -> BA, dense(W1,sigmoid) -> BB ---
  spmm_f32_bf16<<<rowgrid, 256, 0, stream>>>(x, sorted, rowptr, count, BA, N);
  dense_mfma<<<dense_grid, 256, 0, stream>>>((const unsigned short*)BA, Wb + 0 * D * D, b1,
                                             (unsigned short*)BB, N, 1);
  // --- Layer 2 ---
  spmm_bf16_bf16<<<rowgrid, 256, 0, stream>>>(BB, sorted, rowptr, count, BA, N);
  dense_mfma<<<dense_grid, 256, 0, stream>>>((const unsigned short*)BA, Wb + 1 * D * D, b2,
                                             (unsigned short*)BB, N, 1);
  // --- Layer 3 + softmax ---
  spmm_bf16_bf16<<<rowgrid, 256, 0, stream>>>(BB, sorted, rowptr, count, BA, N);
  dense_mfma<<<dense_grid, 256, 0, stream>>>((const unsigned short*)BA, Wb + 2 * D * D, b3,
                                             (unsigned short*)BB, N, 0);
  softmax_rows<<<rowgrid, 256, 0, stream>>>(BB, outf, N);
}

// Round 5
// 394.102 us; speedup vs baseline: 2.9588x; 1.0215x over previous
//
#include <hip/hip_runtime.h>
#include <hip/hip_bf16.h>
#include <cstdint>
#include <cstddef>

#define D 128
#define SCAN_CHUNK 1024

typedef __attribute__((ext_vector_type(8))) __bf16 bf16v8;
typedef __attribute__((ext_vector_type(4))) float f32v4;

// Round-to-nearest-even fp32 -> bf16 (bits), packed pair.
__device__ inline unsigned int pack_bf16x2(float a, float b) {
  unsigned int ua = __float_as_uint(a);
  unsigned int ub = __float_as_uint(b);
  ua = (ua + 0x7fffu + ((ua >> 16) & 1u)) >> 16;
  ub = (ub + 0x7fffu + ((ub >> 16) & 1u)) >> 16;
  return ua | (ub << 16);
}

// ---------------------------------------------------------------------------
// Counting-sort pipeline: build dst-sorted CSR of (src, val) once per call.
// ---------------------------------------------------------------------------
__global__ __launch_bounds__(256) void hist_kernel(
    const int* __restrict__ dst, int* __restrict__ count, int E) {
  int e = blockIdx.x * 256 + threadIdx.x;
  if (e < E) atomicAdd(&count[dst[e]], 1);
}

__global__ __launch_bounds__(256) void scan_blocks(
    const int* __restrict__ count, int* __restrict__ rowptr,
    int* __restrict__ blockSums, int n) {
  __shared__ int sdata[256];
  const int tid = threadIdx.x;
  const int base = blockIdx.x * SCAN_CHUNK;
  int v[4];
#pragma unroll
  for (int k = 0; k < 4; ++k) {
    int idx = base + tid * 4 + k;
    v[k] = (idx < n) ? count[idx] : 0;
  }
  int s = v[0] + v[1] + v[2] + v[3];
  sdata[tid] = s;
  __syncthreads();
  for (int off = 1; off < 256; off <<= 1) {
    int x = (tid >= off) ? sdata[tid - off] : 0;
    __syncthreads();
    sdata[tid] += x;
    __syncthreads();
  }
  int run = sdata[tid] - s;
#pragma unroll
  for (int k = 0; k < 4; ++k) {
    int idx = base + tid * 4 + k;
    if (idx < n) rowptr[idx] = run;
    run += v[k];
  }
  if (tid == 255) blockSums[blockIdx.x] = sdata[255];
}

__global__ __launch_bounds__(256) void scan_top(int* __restrict__ bs, int nblk) {
  __shared__ int sdata[256];
  const int tid = threadIdx.x;
  int v[4];
#pragma unroll
  for (int k = 0; k < 4; ++k) {
    int idx = tid * 4 + k;
    v[k] = (idx < nblk) ? bs[idx] : 0;
  }
  int s = v[0] + v[1] + v[2] + v[3];
  sdata[tid] = s;
  __syncthreads();
  for (int off = 1; off < 256; off <<= 1) {
    int x = (tid >= off) ? sdata[tid - off] : 0;
    __syncthreads();
    sdata[tid] += x;
    __syncthreads();
  }
  int run = sdata[tid] - s;
#pragma unroll
  for (int k = 0; k < 4; ++k) {
    int idx = tid * 4 + k;
    if (idx < nblk) { int t = v[k]; bs[idx] = run; run += t; }
  }
}

__global__ __launch_bounds__(256) void add_offsets(
    int* __restrict__ rowptr, int* __restrict__ cursor,
    const int* __restrict__ bs, int n) {
  int i = blockIdx.x * 256 + threadIdx.x;
  if (i < n) {
    int v = rowptr[i] + bs[i >> 10];
    rowptr[i] = v;
    cursor[i] = v;
  }
}

__global__ __launch_bounds__(256) void scatter_edges(
    const int* __restrict__ src, const int* __restrict__ dst,
    const float* __restrict__ val, int* __restrict__ cursor,
    int2* __restrict__ sorted, int E) {
  int e = blockIdx.x * 256 + threadIdx.x;
  if (e < E) {
    int t = dst[e];
    int pos = atomicAdd(&cursor[t], 1);
    sorted[pos] = make_int2(src[e], __float_as_int(val[e]));
  }
}

// ---------------------------------------------------------------------------
// Weight cast: W (3 matrices, fp32 128x128) -> bf16, once per call.
// ---------------------------------------------------------------------------
__global__ __launch_bounds__(256) void cast_w(
    const float* __restrict__ W1, const float* __restrict__ W2,
    const float* __restrict__ W3, unsigned short* __restrict__ out) {
  const float* src[3] = {W1, W2, W3};
  int m = blockIdx.y;
  int i = blockIdx.x * 256 + threadIdx.x;
  if (i < D * D) {
    unsigned int u = __float_as_uint(src[m][i]);
    out[(size_t)m * D * D + i] =
        (unsigned short)((u + 0x7fffu + ((u >> 16) & 1u)) >> 16);
  }
}

// ---------------------------------------------------------------------------
// Dense transform Y = in @ W^T (no bias/act; bias+activation fused into the
// following SpMM since A@(h W^T)+b == (A@h)W^T+b). bf16 MFMA 16x16x32,
// tile 128x128, identical fragment mapping to the round-4 passing kernel.
// F32IN: stage fp32 input (layer 1 reads x) with convert-on-stage.
// ---------------------------------------------------------------------------
template <int F32IN>
__global__ __launch_bounds__(256) void dense_nt(
    const void* __restrict__ in_v, const unsigned short* __restrict__ Wb,
    unsigned short* __restrict__ out, int M) {
  __shared__ __align__(16) unsigned short Hs[128 * 136];
  __shared__ __align__(16) unsigned short Ws[128 * 136];

  const int tid = threadIdx.x;
  const int w = tid >> 6;
  const int lane = tid & 63;
  const int lane15 = lane & 15;
  const int quad = lane >> 4;
  const int row0 = blockIdx.x * 128;

  const uint4* w16 = (const uint4*)Wb;
#pragma unroll
  for (int it = 0; it < 8; ++it) {
    int c = it * 256 + tid;  // 0..2047
    int r = c >> 4;
    int ck = c & 15;
    *(uint4*)&Ws[r * 136 + ck * 8] = w16[(size_t)r * 16 + ck];
  }

  if (F32IN) {
    const float4* in32 = (const float4*)in_v;  // 32 chunks of 4 floats per row
#pragma unroll
    for (int it = 0; it < 16; ++it) {
      int c = it * 256 + tid;  // 0..4095
      int r = c >> 5;
      int ck = c & 31;
      float4 g = make_float4(0.f, 0.f, 0.f, 0.f);
      if (row0 + r < M) g = in32[(size_t)(row0 + r) * 32 + ck];
      uint2 pk = make_uint2(pack_bf16x2(g.x, g.y), pack_bf16x2(g.z, g.w));
      *(uint2*)&Hs[r * 136 + ck * 4] = pk;
    }
  } else {
    const uint4* in16 = (const uint4*)in_v;  // 16 chunks per bf16 row
#pragma unroll
    for (int it = 0; it < 8; ++it) {
      int c = it * 256 + tid;
      int r = c >> 4;
      int ck = c & 15;
      uint4 g = make_uint4(0, 0, 0, 0);
      if (row0 + r < M) g = in16[(size_t)(row0 + r) * 16 + ck];
      *(uint4*)&Hs[r * 136 + ck * 8] = g;
    }
  }
  __syncthreads();

  f32v4 acc[2][8];
#pragma unroll
  for (int mt = 0; mt < 2; ++mt)
#pragma unroll
    for (int nt = 0; nt < 8; ++nt) acc[mt][nt] = (f32v4){0.f, 0.f, 0.f, 0.f};

#pragma unroll
  for (int kt = 0; kt < 4; ++kt) {
    const int ko = kt * 32 + quad * 8;
    bf16v8 a0 = *(const bf16v8*)&Hs[(w * 32 + lane15) * 136 + ko];
    bf16v8 a1 = *(const bf16v8*)&Hs[(w * 32 + 16 + lane15) * 136 + ko];
#pragma unroll
    for (int nt = 0; nt < 8; ++nt) {
      bf16v8 b = *(const bf16v8*)&Ws[(nt * 16 + lane15) * 136 + ko];
      acc[0][nt] = __builtin_amdgcn_mfma_f32_16x16x32_bf16(a0, b, acc[0][nt], 0, 0, 0);
      acc[1][nt] = __builtin_amdgcn_mfma_f32_16x16x32_bf16(a1, b, acc[1][nt], 0, 0, 0);
    }
  }

#pragma unroll
  for (int mt = 0; mt < 2; ++mt) {
#pragma unroll
    for (int r = 0; r < 4; ++r) {
      int grow = row0 + w * 32 + mt * 16 + quad * 4 + r;
      if (grow < M) {
#pragma unroll
        for (int nt = 0; nt < 8; ++nt) {
          unsigned int u = __float_as_uint(acc[mt][nt][r]);
          out[(size_t)grow * D + nt * 16 + lane15] =
              (unsigned short)((u + 0x7fffu + ((u >> 16) & 1u)) >> 16);
        }
      }
    }
  }
}

// ---------------------------------------------------------------------------
// Fused SpMM epilogues. One wave per row; lane owns dims (2*lane, 2*lane+1).
// out[row] = epilogue( sum_j val_j * Y[src_j] + bias ).
// MODE 0: sigmoid -> bf16 packed.  MODE 1: row softmax -> fp32 float2.
// ---------------------------------------------------------------------------
template <int MODE>
__global__ __launch_bounds__(256) void spmm_fused(
    const unsigned int* __restrict__ h, const int2* __restrict__ sorted,
    const int* __restrict__ rowptr, const int* __restrict__ count,
    const float* __restrict__ bias, void* __restrict__ out_v, int n) {
  int wave = threadIdx.x >> 6;
  int lane = threadIdx.x & 63;
  int row = blockIdx.x * 4 + wave;
  if (row >= n) return;
  int start = rowptr[row];
  int len = count[row];
  float a0 = 0.f, a1 = 0.f;
  int j = 0;
  for (; j + 2 <= len; j += 2) {
    int2 e0 = sorted[start + j];
    int2 e1 = sorted[start + j + 1];
    unsigned int u0 = h[(size_t)e0.x * 64 + lane];
    unsigned int u1 = h[(size_t)e1.x * 64 + lane];
    float v0 = __int_as_float(e0.y);
    float v1 = __int_as_float(e1.y);
    a0 += v0 * __uint_as_float(u0 << 16);
    a1 += v0 * __uint_as_float(u0 & 0xffff0000u);
    a0 += v1 * __uint_as_float(u1 << 16);
    a1 += v1 * __uint_as_float(u1 & 0xffff0000u);
  }
  if (j < len) {
    int2 e0 = sorted[start + j];
    unsigned int u0 = h[(size_t)e0.x * 64 + lane];
    float v0 = __int_as_float(e0.y);
    a0 += v0 * __uint_as_float(u0 << 16);
    a1 += v0 * __uint_as_float(u0 & 0xffff0000u);
  }
  float2 bb = ((const float2*)bias)[lane];
  a0 += bb.x;
  a1 += bb.y;
  if (MODE == 0) {
    a0 = 1.0f / (1.0f + __expf(-a0));
    a1 = 1.0f / (1.0f + __expf(-a1));
    ((unsigned int*)out_v)[(size_t)row * 64 + lane] = pack_bf16x2(a0, a1);
  } else {
    float m = fmaxf(a0, a1);
#pragma unroll
    for (int off = 32; off; off >>= 1) m = fmaxf(m, __shfl_xor(m, off));
    float ea = __expf(a0 - m);
    float eb = __expf(a1 - m);
    float s = ea + eb;
#pragma unroll
    for (int off = 32; off; off >>= 1) s += __shfl_xor(s, off);
    float inv = 1.0f / s;
    ((float2*)out_v)[(size_t)row * 64 + lane] = make_float2(ea * inv, eb * inv);
  }
}

// ---------------------------------------------------------------------------
extern "C" void kernel_launch(void* const* d_in, const int* in_sizes, int n_in,
                              void* d_out, int out_size, void* d_ws, size_t ws_size,
                              hipStream_t stream) {
  const float* x  = (const float*)d_in[0];
  const float* ev = (const float*)d_in[1];
  const float* W1 = (const float*)d_in[2];
  const float* b1 = (const float*)d_in[3];
  const float* W2 = (const float*)d_in[4];
  const float* b2 = (const float*)d_in[5];
  const float* W3 = (const float*)d_in[6];
  const float* b3 = (const float*)d_in[7];
  const int* es = (const int*)d_in[8];
  const int* ed = (const int*)d_in[9];

  const int N = in_sizes[0] / D;
  const int E = in_sizes[1];

  // Workspace layout (all 16B-aligned)
  char* p = (char*)d_ws;
  unsigned int* BA = (unsigned int*)p; p += (size_t)N * 64 * sizeof(unsigned int);
  unsigned int* BB = (unsigned int*)p; p += (size_t)N * 64 * sizeof(unsigned int);
  int2* sorted = (int2*)p;          p += (size_t)E * sizeof(int2);
  unsigned short* Wb = (unsigned short*)p; p += 3 * (size_t)D * D * sizeof(unsigned short);
  int* count  = (int*)p;            p += (size_t)N * sizeof(int);
  int* rowptr = (int*)p;            p += (size_t)N * sizeof(int);
  int* cursor = (int*)p;            p += (size_t)N * sizeof(int);
  int* blockSums = (int*)p;         p += 1024 * sizeof(int);

  const int eblk = (E + 255) / 256;
  const int nblk256 = (N + 255) / 256;
  const int nblkScan = (N + SCAN_CHUNK - 1) / SCAN_CHUNK;
  const int rowgrid = (N + 3) / 4;
  const int dense_grid = (N + 127) / 128;

  // --- Build dst-sorted CSR + bf16 weights ---
  (void)hipMemsetAsync(count, 0, (size_t)N * sizeof(int), stream);
  hist_kernel<<<eblk, 256, 0, stream>>>(ed, count, E);
  cast_w<<<dim3((D * D + 255) / 256, 3), 256, 0, stream>>>(W1, W2, W3, Wb);
  scan_blocks<<<nblkScan, 256, 0, stream>>>(count, rowptr, blockSums, N);
  scan_top<<<1, 256, 0, stream>>>(blockSums, nblkScan);
  add_offsets<<<nblk256, 256, 0, stream>>>(rowptr, cursor, blockSums, N);
  scatter_edges<<<eblk, 256, 0, stream>>>(es, ed, ev, cursor, sorted, E);

  // --- Layer 1: Y1 = x@W1^T (fp32 in), h1 = sigmoid(A@Y1 + b1) ---
  dense_nt<1><<<dense_grid, 256, 0, stream>>>(x, Wb + 0 * D * D,
                                              (unsigned short*)BA, N);
  spmm_fused<0><<<rowgrid, 256, 0, stream>>>(BA, sorted, rowptr, count, b1, BB, N);
  // --- Layer 2 ---
  dense_nt<0><<<dense_grid, 256, 0, stream>>>(BB, Wb + 1 * D * D,
                                              (unsigned short*)BA, N);
  spmm_fused<0><<<rowgrid, 256, 0, stream>>>(BA, sorted, rowptr, count, b2, BB, N);
  // --- Layer 3: Y3 = h2@W3^T, out = softmax(A@Y3 + b3) ---
  dense_nt<0><<<dense_grid, 256, 0, stream>>>(BB, Wb + 2 * D * D,
                                              (unsigned short*)BA, N);
  spmm_fused<1><<<rowgrid, 256, 0, stream>>>(BA, sorted, rowptr, count, b3, d_out, N);
}